// Round 1
// baseline (1721.719 us; speedup 1.0000x reference)
//
#include <hip/hip_runtime.h>
#include <hip/hip_bf16.h>

constexpr int F_N   = 20000;
constexpr int S_N   = 60000;
constexpr int U_N   = 2000;
constexpr int I_N   = 2000;
constexpr int NSUPN = 64000;
constexpr int E_NN  = NSUPN * 8;   // 512000
// HID=128, NH=8, DH=16, FFN=512

// ---------------- gather / prep ----------------

__global__ void k_gather128(const float* __restrict__ tab, const int* __restrict__ idx,
                            float* __restrict__ out, int M) {
  int t = blockIdx.x * 256 + threadIdx.x;
  if (t >= M * 128) return;
  int r = t >> 7, c = t & 127;
  out[t] = tab[(size_t)idx[r] * 128 + c];
}

// mean of 8 predecessor feature rows, only for supernodes [S, NSUP)
__global__ void k_fmean(const float* __restrict__ feat, const int* __restrict__ esrc,
                        float* __restrict__ fm) {
  int n = S_N + blockIdx.x;
  int c = threadIdx.x;
  float s = 0.f;
#pragma unroll
  for (int j = 0; j < 8; ++j) s += feat[(size_t)esrc[n * 8 + j] * 128 + c];
  fm[(size_t)blockIdx.x * 128 + c] = s * 0.125f;  // cnt == 8 exactly
}

__global__ void k_addgather(const float* __restrict__ tab, const int* __restrict__ idx,
                            const float* __restrict__ fm, int fmoff,
                            float* __restrict__ out, int M) {
  int t = blockIdx.x * 256 + threadIdx.x;
  if (t >= M * 128) return;
  int r = t >> 7, c = t & 127;
  out[t] = tab[(size_t)idx[r] * 128 + c] + fm[(size_t)(fmoff + r) * 128 + c];
}

// W [NH=8, HID=128, DH=16] -> Wf [128, 128] with Wf[d][h*16+e] = W[h][d][e]
__global__ void k_build_wf(const float* __restrict__ W, float* __restrict__ Wf) {
  int t = blockIdx.x * 256 + threadIdx.x;
  if (t >= 128 * 128) return;
  int d = t >> 7, c = t & 127;
  Wf[t] = W[((c >> 4) << 11) + (d << 4) + (c & 15)];
}

// ---------------- generic row-block GEMM: C[M,128] = A[M,K] @ B[K,128] (+bias) ----------------
template<bool GATHER, bool BIAS>
__global__ __launch_bounds__(128)
void k_gemm_rows(const float* __restrict__ A, const int* __restrict__ gidx, int ldA,
                 const float* __restrict__ B, const float* __restrict__ bias,
                 float* __restrict__ C, int K) {
  __shared__ float As[16 * 256];
  int r0 = blockIdx.x * 16;
  int tid = threadIdx.x;
  for (int idx = tid; idx < 16 * K; idx += 128) {
    int r = idx / K, k = idx - r * K;
    int row = r0 + r;
    size_t abase = GATHER ? (size_t)gidx[row] * ldA : (size_t)row * ldA;
    As[r * K + k] = A[abase + k];
  }
  __syncthreads();
  float acc[16];
#pragma unroll
  for (int r = 0; r < 16; ++r) acc[r] = 0.f;
  int c = tid;
  for (int k = 0; k < K; ++k) {
    float w = B[k * 128 + c];
#pragma unroll
    for (int r = 0; r < 16; ++r) acc[r] += As[r * K + k] * w;
  }
  float bv = BIAS ? bias[c] : 0.f;
#pragma unroll
  for (int r = 0; r < 16; ++r) C[(size_t)(r0 + r) * 128 + c] = acc[r] + bv;
}

// ---------------- per-head attention logits: el[r,h] = sum_e z[r,h*16+e]*a[h,e] ----------------
__global__ void k_el(const float* __restrict__ z, const float* __restrict__ a,
                     float* __restrict__ el, int N) {
  int t = blockIdx.x * 256 + threadIdx.x;
  if (t >= N * 8) return;
  int r = t >> 3, h = t & 7;
  const float* zr = z + (size_t)r * 128 + h * 16;
  const float* ah = a + h * 16;
  float s = 0.f;
#pragma unroll
  for (int e = 0; e < 16; ++e) s += zr[e] * ah[e];
  el[t] = s;
}

// ---------------- attention, fixed in-degree 8 (dst segments contiguous) ----------------
__global__ __launch_bounds__(128)
void k_attn8(const float* __restrict__ zsrc, const float* __restrict__ el,
             const float* __restrict__ er, const int* __restrict__ esrc,
             const float* __restrict__ ew, const float* __restrict__ ae,
             float* __restrict__ hout) {
  int n = blockIdx.x;
  int c = threadIdx.x;
  int h = c >> 4;
  float aeh = ae[h];
  float erv = er[n * 8 + h];
  int s[8]; float evv[8];
  float m = -1e30f;
#pragma unroll
  for (int j = 0; j < 8; ++j) {
    int eid = n * 8 + j;
    s[j] = esrc[eid];
    float x = el[s[j] * 8 + h] + erv + ew[eid] * aeh;
    x = x > 0.f ? x : 0.2f * x;       // leaky_relu 0.2
    evv[j] = x;
    m = fmaxf(m, x);
  }
  float den = 0.f;
#pragma unroll
  for (int j = 0; j < 8; ++j) { evv[j] = __expf(evv[j] - m); den += evv[j]; }
  float inv = 1.f / fmaxf(den, 1e-9f);
  float acc = 0.f;
#pragma unroll
  for (int j = 0; j < 8; ++j) acc += evv[j] * zsrc[(size_t)s[j] * 128 + c];
  acc *= inv;
  hout[(size_t)n * 128 + c] = acc > 0.f ? acc : (__expf(acc) - 1.f);  // elu
}

// ---------------- attention, CSR (variable degree; dst = random e_src) ----------------
__global__ __launch_bounds__(128)
void k_attn_csr(const float* __restrict__ zsrc, const float* __restrict__ el,
                const float* __restrict__ er, const int* __restrict__ rowptr,
                const int* __restrict__ eids, const int* __restrict__ rsrc,
                const float* __restrict__ ew, const float* __restrict__ ae,
                float* __restrict__ hout) {
  int n = blockIdx.x;
  int c = threadIdx.x;
  int h = c >> 4;
  int beg = rowptr[n], end = rowptr[n + 1];
  float aeh = ae[h];
  float erv = er[n * 8 + h];
  float m = -1e30f;
  for (int p = beg; p < end; ++p) {
    int eid = eids[p];
    float x = el[rsrc[eid] * 8 + h] + erv + ew[eid] * aeh;
    x = x > 0.f ? x : 0.2f * x;
    m = fmaxf(m, x);
  }
  float den = 0.f;
  for (int p = beg; p < end; ++p) {
    int eid = eids[p];
    float x = el[rsrc[eid] * 8 + h] + erv + ew[eid] * aeh;
    x = x > 0.f ? x : 0.2f * x;
    den += __expf(x - m);
  }
  float acc = 0.f;
  for (int p = beg; p < end; ++p) {
    int eid = eids[p];
    int sv = rsrc[eid];
    float x = el[sv * 8 + h] + erv + ew[eid] * aeh;
    x = x > 0.f ? x : 0.2f * x;
    acc += __expf(x - m) * zsrc[(size_t)sv * 128 + c];
  }
  acc /= fmaxf(den, 1e-9f);
  hout[(size_t)n * 128 + c] = acc > 0.f ? acc : (__expf(acc) - 1.f);
}

// ---------------- fused LayerNorm + FFN (+residual): out = h + relu(LN(h)@W1+b1)@W2+b2 ----------------
__global__ __launch_bounds__(256)
void k_ln_ffn(const float* __restrict__ h, const float* __restrict__ g, const float* __restrict__ b,
              const float* __restrict__ W1, const float* __restrict__ b1,
              const float* __restrict__ W2, const float* __restrict__ b2,
              float* __restrict__ out) {
  __shared__ float hs[16][128];
  __shared__ float ls[16][128];
  __shared__ float mid[16][512];
  int r0 = blockIdx.x * 16;
  int tid = threadIdx.x;
  for (int idx = tid; idx < 16 * 128; idx += 256) {
    int r = idx >> 7, c = idx & 127;
    hs[r][c] = h[(size_t)(r0 + r) * 128 + c];
  }
  __syncthreads();
  {
    int r = tid >> 4, lane = tid & 15;
    float sum = 0.f, sq = 0.f;
    for (int c = lane; c < 128; c += 16) { float v = hs[r][c]; sum += v; sq += v * v; }
#pragma unroll
    for (int o = 8; o >= 1; o >>= 1) { sum += __shfl_xor(sum, o); sq += __shfl_xor(sq, o); }
    float mu = sum * (1.f / 128.f);
    float var = sq * (1.f / 128.f) - mu * mu;
    float inv = rsqrtf(var + 1e-6f);
    for (int c = lane; c < 128; c += 16)
      ls[r][c] = (hs[r][c] - mu) * inv * g[c] + b[c];
  }
  __syncthreads();
  // GEMM1: mid[16,512] = relu(ls @ W1 + b1); thread = 4 rows x 8 cols
  {
    int rr = (tid >> 6) * 4;
    int c0 = (tid & 63) * 8;
    float acc[4][8];
#pragma unroll
    for (int r = 0; r < 4; ++r)
#pragma unroll
      for (int j = 0; j < 8; ++j) acc[r][j] = 0.f;
    for (int k = 0; k < 128; ++k) {
      const float* wr = W1 + (size_t)k * 512 + c0;
      float4 w0 = *(const float4*)wr;
      float4 w1 = *(const float4*)(wr + 4);
      float wv[8] = {w0.x, w0.y, w0.z, w0.w, w1.x, w1.y, w1.z, w1.w};
      float av[4] = {ls[rr][k], ls[rr + 1][k], ls[rr + 2][k], ls[rr + 3][k]};
#pragma unroll
      for (int r = 0; r < 4; ++r)
#pragma unroll
        for (int j = 0; j < 8; ++j) acc[r][j] += av[r] * wv[j];
    }
#pragma unroll
    for (int j = 0; j < 8; ++j) {
      float bb = b1[c0 + j];
#pragma unroll
      for (int r = 0; r < 4; ++r) mid[rr + r][c0 + j] = fmaxf(acc[r][j] + bb, 0.f);
    }
  }
  __syncthreads();
  // GEMM2: out = hs + mid @ W2 + b2; thread = 2 rows x 4 cols
  {
    int rr = (tid >> 5) * 2;
    int c0 = (tid & 31) * 4;
    float acc[2][4];
#pragma unroll
    for (int r = 0; r < 2; ++r)
#pragma unroll
      for (int j = 0; j < 4; ++j) acc[r][j] = 0.f;
    for (int k = 0; k < 512; ++k) {
      float4 w = *(const float4*)(W2 + (size_t)k * 128 + c0);
      float wv[4] = {w.x, w.y, w.z, w.w};
      float a0 = mid[rr][k], a1 = mid[rr + 1][k];
#pragma unroll
      for (int j = 0; j < 4; ++j) { acc[0][j] += a0 * wv[j]; acc[1][j] += a1 * wv[j]; }
    }
#pragma unroll
    for (int j = 0; j < 4; ++j) {
      float bb = b2[c0 + j];
#pragma unroll
      for (int r = 0; r < 2; ++r)
        out[(size_t)(r0 + rr + r) * 128 + c0 + j] = hs[rr + r][c0 + j] + acc[r][j] + bb;
    }
  }
}

// ---------------- final head: out[S,2] = sup[:S] @ whW + whb ----------------
__global__ __launch_bounds__(256)
void k_whout(const float* __restrict__ sup, const float* __restrict__ whW,
             const float* __restrict__ whb, float* __restrict__ out) {
  int wv = threadIdx.x >> 6, lane = threadIdx.x & 63;
  int r = blockIdx.x * 4 + wv;
  if (r >= S_N) return;
  const float* row = sup + (size_t)r * 128;
  float a0 = 0.f, a1 = 0.f;
  for (int d = lane; d < 128; d += 64) {
    float v = row[d];
    a0 += v * whW[d * 2];
    a1 += v * whW[d * 2 + 1];
  }
#pragma unroll
  for (int o = 32; o >= 1; o >>= 1) { a0 += __shfl_xor(a0, o); a1 += __shfl_xor(a1, o); }
  if (lane == 0) { out[r * 2] = a0 + whb[0]; out[r * 2 + 1] = a1 + whb[1]; }
}

// ---------------- CSR build ----------------
__global__ void k_count(const int* __restrict__ esrc, int* __restrict__ counts) {
  int t = blockIdx.x * 256 + threadIdx.x;
  if (t < E_NN) atomicAdd(&counts[esrc[t]], 1);
}

__global__ __launch_bounds__(1024)
void k_scan(const int* __restrict__ counts, int* __restrict__ rowptr) {
  __shared__ int wsum[16];
  __shared__ int carry;
  int tid = threadIdx.x, lane = tid & 63, w = tid >> 6;
  if (tid == 0) { carry = 0; rowptr[0] = 0; }
  __syncthreads();
  for (int base = 0; base < F_N; base += 1024) {
    int i = base + tid;
    int v = (i < F_N) ? counts[i] : 0;
    int s = v;
#pragma unroll
    for (int o = 1; o < 64; o <<= 1) { int t2 = __shfl_up(s, o); if (lane >= o) s += t2; }
    if (lane == 63) wsum[w] = s;
    __syncthreads();
    if (w == 0) {
      int t2 = (lane < 16) ? wsum[lane] : 0;
#pragma unroll
      for (int o = 1; o < 16; o <<= 1) { int u = __shfl_up(t2, o); if (lane >= o) t2 += u; }
      if (lane < 16) wsum[lane] = t2;
    }
    __syncthreads();
    int add = carry + (w > 0 ? wsum[w - 1] : 0);
    if (i < F_N) rowptr[i + 1] = s + add;
    int total = wsum[15];
    __syncthreads();
    if (tid == 0) carry += total;
    __syncthreads();
  }
}

__global__ void k_fill(const int* __restrict__ esrc, const int* __restrict__ rowptr,
                       int* __restrict__ fill, int* __restrict__ eids) {
  int t = blockIdx.x * 256 + threadIdx.x;
  if (t < E_NN) {
    int sv = esrc[t];
    int p = atomicAdd(&fill[sv], 1);
    eids[rowptr[sv] + p] = t;
  }
}

// ---------------- launch ----------------
extern "C" void kernel_launch(void* const* d_in, const int* in_sizes, int n_in,
                              void* d_out, int out_size, void* d_ws, size_t ws_size,
                              hipStream_t stream) {
  const int* fid = (const int*)d_in[0];
  const int* sid = (const int*)d_in[1];
  const int* uid = (const int*)d_in[2];
  const int* iid = (const int*)d_in[3];
  const int* e_src = (const int*)d_in[4];
  const int* e_dst = (const int*)d_in[5];
  const float* e_w = (const float*)d_in[6];
  const float* feat_tab = (const float*)d_in[7];
  const float* sent_tab = (const float*)d_in[8];
  const float* user_tab = (const float*)d_in[9];
  const float* item_tab = (const float*)d_in[10];
  const float* Wsp = (const float*)d_in[11];
  const float* bsp = (const float*)d_in[12];
  const float* Wup = (const float*)d_in[13];
  const float* Wip = (const float*)d_in[14];
  const float* w2s[10]; for (int i = 0; i < 10; ++i) w2s[i] = (const float*)d_in[15 + i];
  const float* s2w[10]; for (int i = 0; i < 10; ++i) s2w[i] = (const float*)d_in[25 + i];
  const float* whW = (const float*)d_in[35];
  const float* whb = (const float*)d_in[36];
  float* out = (float*)d_out;

  char* wp = (char*)d_ws;
  auto alloc = [&](size_t nbytes) -> void* {
    void* p = (void*)wp;
    wp += (nbytes + 255) & ~(size_t)255;
    return p;
  };
  float* featA = (float*)alloc((size_t)F_N * 128 * 4);
  float* supA  = (float*)alloc((size_t)NSUPN * 128 * 4);
  float* zf    = (float*)alloc((size_t)F_N * 128 * 4);
  float* zs    = (float*)alloc((size_t)NSUPN * 128 * 4);
  float* hbuf  = (float*)alloc((size_t)NSUPN * 128 * 4);
  float* elbig = (float*)alloc((size_t)NSUPN * 8 * 4);
  float* erbig = (float*)alloc((size_t)NSUPN * 8 * 4);
  float* wfA   = (float*)alloc(128 * 128 * 4);
  float* wfB   = (float*)alloc(128 * 128 * 4);
  float* atmpu = (float*)alloc((size_t)U_N * 128 * 4);
  float* atmpi = (float*)alloc((size_t)I_N * 128 * 4);
  float* fm    = (float*)alloc((size_t)(U_N + I_N) * 128 * 4);
  int* rowptr  = (int*)alloc((size_t)(F_N + 1) * 4);
  int* cnts    = (int*)alloc((size_t)2 * F_N * 4);  // counts + fill, contiguous
  int* eids    = (int*)alloc((size_t)E_NN * 4);

  // ---- stage A: init states ----
  k_gather128<<<(F_N * 128 + 255) / 256, 256, 0, stream>>>(feat_tab, fid, featA, F_N);
  k_fmean<<<U_N + I_N, 128, 0, stream>>>(featA, e_src, fm);
  k_build_wf<<<64, 256, 0, stream>>>(w2s[0], wfA);
  k_build_wf<<<64, 256, 0, stream>>>(s2w[0], wfB);
  k_gemm_rows<true, true><<<S_N / 16, 128, 0, stream>>>(sent_tab, sid, 256, Wsp, bsp, supA, 256);
  k_addgather<<<(U_N * 128 + 255) / 256, 256, 0, stream>>>(user_tab, uid, fm, 0, atmpu, U_N);
  k_gemm_rows<false, false><<<U_N / 16, 128, 0, stream>>>(atmpu, nullptr, 128, Wup, nullptr,
                                                          supA + (size_t)S_N * 128, 128);
  k_addgather<<<(I_N * 128 + 255) / 256, 256, 0, stream>>>(item_tab, iid, fm, U_N, atmpi, I_N);
  k_gemm_rows<false, false><<<I_N / 16, 128, 0, stream>>>(atmpi, nullptr, 128, Wip, nullptr,
                                                          supA + (size_t)(S_N + U_N) * 128, 128);
  // ---- CSR over e_src (for the s2w direction) ----
  hipMemsetAsync(cnts, 0, (size_t)2 * F_N * 4, stream);
  k_count<<<(E_NN + 255) / 256, 256, 0, stream>>>(e_src, cnts);
  k_scan<<<1, 1024, 0, stream>>>(cnts, rowptr);
  k_fill<<<(E_NN + 255) / 256, 256, 0, stream>>>(e_src, rowptr, cnts + F_N, eids);

  auto gat_w2s = [&](const float* hsrc, const float* hdst, float* outp) {
    k_gemm_rows<false, false><<<F_N / 16, 128, 0, stream>>>(hsrc, nullptr, 128, wfA, nullptr, zf, 128);
    k_gemm_rows<false, false><<<NSUPN / 16, 128, 0, stream>>>(hdst, nullptr, 128, wfA, nullptr, zs, 128);
    k_el<<<(F_N * 8 + 255) / 256, 256, 0, stream>>>(zf, w2s[1], elbig, F_N);
    k_el<<<(NSUPN * 8 + 255) / 256, 256, 0, stream>>>(zs, w2s[2], erbig, NSUPN);
    k_attn8<<<NSUPN, 128, 0, stream>>>(zf, elbig, erbig, e_src, e_w, w2s[3], hbuf);
    k_ln_ffn<<<NSUPN / 16, 256, 0, stream>>>(hbuf, w2s[8], w2s[9], w2s[4], w2s[5], w2s[6], w2s[7], outp);
  };
  auto gat_s2w = [&](const float* hsrc, const float* hdst, float* outp) {
    k_gemm_rows<false, false><<<NSUPN / 16, 128, 0, stream>>>(hsrc, nullptr, 128, wfB, nullptr, zs, 128);
    k_gemm_rows<false, false><<<F_N / 16, 128, 0, stream>>>(hdst, nullptr, 128, wfB, nullptr, zf, 128);
    k_el<<<(NSUPN * 8 + 255) / 256, 256, 0, stream>>>(zs, s2w[1], elbig, NSUPN);
    k_el<<<(F_N * 8 + 255) / 256, 256, 0, stream>>>(zf, s2w[2], erbig, F_N);
    k_attn_csr<<<F_N, 128, 0, stream>>>(zs, elbig, erbig, rowptr, eids, e_dst, e_w, s2w[3], hbuf);
    k_ln_ffn<<<F_N / 16, 256, 0, stream>>>(hbuf, s2w[8], s2w[9], s2w[4], s2w[5], s2w[6], s2w[7], outp);
  };

  // sup = w2s(feat, sup); feat = s2w(sup, feat); sup = w2s(feat, sup)
  gat_w2s(featA, supA, supA);   // ln_ffn only reads hbuf -> in-place safe
  gat_s2w(supA, featA, featA);
  gat_w2s(featA, supA, supA);

  k_whout<<<(S_N + 3) / 4, 256, 0, stream>>>(supA, whW, whb, out);
}

// Round 2
// 882.037 us; speedup vs baseline: 1.9520x; 1.9520x over previous
//
#include <hip/hip_runtime.h>
#include <hip/hip_bf16.h>

constexpr int F_N   = 20000;
constexpr int S_N   = 60000;
constexpr int U_N   = 2000;
constexpr int I_N   = 2000;
constexpr int NSUPN = 64000;
constexpr int E_NN  = NSUPN * 8;   // 512000
// HID=128, NH=8, DH=16, FFN=512

typedef __bf16 bf16_t;
typedef bf16_t bf16x8 __attribute__((ext_vector_type(8)));
typedef float  f32x4  __attribute__((ext_vector_type(4)));

// ---------------- gather / prep ----------------

__global__ void k_gather128(const float* __restrict__ tab, const int* __restrict__ idx,
                            float* __restrict__ out, int M) {
  int t = blockIdx.x * 256 + threadIdx.x;
  if (t >= M * 128) return;
  int r = t >> 7, c = t & 127;
  out[t] = tab[(size_t)idx[r] * 128 + c];
}

__global__ void k_fmean(const float* __restrict__ feat, const int* __restrict__ esrc,
                        float* __restrict__ fm) {
  int n = S_N + blockIdx.x;
  int c = threadIdx.x;
  float s = 0.f;
#pragma unroll
  for (int j = 0; j < 8; ++j) s += feat[(size_t)esrc[n * 8 + j] * 128 + c];
  fm[(size_t)blockIdx.x * 128 + c] = s * 0.125f;  // cnt == 8 exactly
}

__global__ void k_addgather(const float* __restrict__ tab, const int* __restrict__ idx,
                            const float* __restrict__ fm, int fmoff,
                            float* __restrict__ out, int M) {
  int t = blockIdx.x * 256 + threadIdx.x;
  if (t >= M * 128) return;
  int r = t >> 7, c = t & 127;
  out[t] = tab[(size_t)idx[r] * 128 + c] + fm[(size_t)(fmoff + r) * 128 + c];
}

// transpose-convert: out_bf16[c*K + k] = in_f32[k*C + c]
__global__ void k_conv_t(const float* __restrict__ in, bf16_t* __restrict__ out, int K, int C) {
  int t = blockIdx.x * 256 + threadIdx.x;
  if (t >= K * C) return;
  int c = t / K, k = t - c * K;
  out[t] = (bf16_t)in[(size_t)k * C + c];
}

// W [NH=8, HID=128, DH=16] -> Wft bf16 [col=128][d=128], Wft[col][d] = W[col>>4][d][col&15]
__global__ void k_build_wft(const float* __restrict__ W, bf16_t* __restrict__ out) {
  int t = blockIdx.x * 256 + threadIdx.x;
  if (t >= 128 * 128) return;
  int col = t >> 7, d = t & 127;
  out[t] = (bf16_t)W[((col >> 4) << 11) + (d << 4) + (col & 15)];
}

// ---------------- fp32 row-block GEMM (init projections only) ----------------
template<bool GATHER, bool BIAS>
__global__ __launch_bounds__(128)
void k_gemm_rows(const float* __restrict__ A, const int* __restrict__ gidx, int ldA,
                 const float* __restrict__ B, const float* __restrict__ bias,
                 float* __restrict__ C, int K) {
  __shared__ float As[16 * 256];
  int r0 = blockIdx.x * 16;
  int tid = threadIdx.x;
  for (int idx = tid; idx < 16 * K; idx += 128) {
    int r = idx / K, k = idx - r * K;
    int row = r0 + r;
    size_t abase = GATHER ? (size_t)gidx[row] * ldA : (size_t)row * ldA;
    As[r * K + k] = A[abase + k];
  }
  __syncthreads();
  float acc[16];
#pragma unroll
  for (int r = 0; r < 16; ++r) acc[r] = 0.f;
  int c = tid;
  for (int k = 0; k < K; ++k) {
    float w = B[k * 128 + c];
#pragma unroll
    for (int r = 0; r < 16; ++r) acc[r] += As[r * K + k] * w;
  }
  float bv = BIAS ? bias[c] : 0.f;
#pragma unroll
  for (int r = 0; r < 16; ++r) C[(size_t)(r0 + r) * 128 + c] = acc[r] + bv;
}

// ---------------- MFMA z-projection: z[N,128] = bf16(h) @ Wft^T (fp32 out) ----------------
__global__ __launch_bounds__(256)
void k_zproj_mfma(const float* __restrict__ h, const bf16_t* __restrict__ Wft,
                  float* __restrict__ z) {
  __shared__ bf16_t hb[32][128];
  int r0 = blockIdx.x * 32;
  int tid = threadIdx.x;
  // stage 32x128 as bf16, XOR-swizzled (elem ^= (row&7)<<3)
  for (int i = 0; i < 2; ++i) {
    int cid = tid + 256 * i;           // 512 chunks of 8 elems
    int r = cid >> 4, c0 = (cid & 15) * 8;
    const float* src = &h[(size_t)(r0 + r) * 128 + c0];
    float4 v0 = *(const float4*)src;
    float4 v1 = *(const float4*)(src + 4);
    bf16x8 bv = { (bf16_t)v0.x, (bf16_t)v0.y, (bf16_t)v0.z, (bf16_t)v0.w,
                  (bf16_t)v1.x, (bf16_t)v1.y, (bf16_t)v1.z, (bf16_t)v1.w };
    *(bf16x8*)&hb[r][c0 ^ ((r & 7) << 3)] = bv;
  }
  __syncthreads();
  int w = tid >> 6, l = tid & 63, la = l & 15, lb = l >> 4;
  int swz = (la & 7) << 3;
  f32x4 acc[2][2] = {};
#pragma unroll
  for (int ks = 0; ks < 4; ++ks) {
    int k0 = ks * 32 + lb * 8;
    bf16x8 a0 = *(const bf16x8*)&hb[la][k0 ^ swz];
    bf16x8 a1 = *(const bf16x8*)&hb[16 + la][k0 ^ swz];
#pragma unroll
    for (int ct = 0; ct < 2; ++ct) {
      int col = w * 32 + ct * 16 + la;
      bf16x8 bb = *(const bf16x8*)&Wft[(size_t)col * 128 + k0];
      acc[0][ct] = __builtin_amdgcn_mfma_f32_16x16x32_bf16(a0, bb, acc[0][ct], 0, 0, 0);
      acc[1][ct] = __builtin_amdgcn_mfma_f32_16x16x32_bf16(a1, bb, acc[1][ct], 0, 0, 0);
    }
  }
#pragma unroll
  for (int ct = 0; ct < 2; ++ct) {
    int col = w * 32 + ct * 16 + la;
#pragma unroll
    for (int rt = 0; rt < 2; ++rt)
#pragma unroll
      for (int r = 0; r < 4; ++r)
        z[(size_t)(r0 + rt * 16 + lb * 4 + r) * 128 + col] = acc[rt][ct][r];
  }
}

// ---------------- per-head attention logits ----------------
__global__ void k_el(const float* __restrict__ z, const float* __restrict__ a,
                     float* __restrict__ el, int N) {
  int t = blockIdx.x * 256 + threadIdx.x;
  if (t >= N * 8) return;
  int r = t >> 3, h = t & 7;
  const float* zr = z + (size_t)r * 128 + h * 16;
  const float* ah = a + h * 16;
  float s = 0.f;
#pragma unroll
  for (int e = 0; e < 16; ++e) s += zr[e] * ah[e];
  el[t] = s;
}

// ---------------- attention, fixed in-degree 8 ----------------
__global__ __launch_bounds__(128)
void k_attn8(const float* __restrict__ zsrc, const float* __restrict__ el,
             const float* __restrict__ er, const int* __restrict__ esrc,
             const float* __restrict__ ew, const float* __restrict__ ae,
             float* __restrict__ hout) {
  int n = blockIdx.x;
  int c = threadIdx.x;
  int h = c >> 4;
  float aeh = ae[h];
  float erv = er[n * 8 + h];
  int s[8]; float evv[8];
  float m = -1e30f;
#pragma unroll
  for (int j = 0; j < 8; ++j) {
    int eid = n * 8 + j;
    s[j] = esrc[eid];
    float x = el[s[j] * 8 + h] + erv + ew[eid] * aeh;
    x = x > 0.f ? x : 0.2f * x;
    evv[j] = x;
    m = fmaxf(m, x);
  }
  float den = 0.f;
#pragma unroll
  for (int j = 0; j < 8; ++j) { evv[j] = __expf(evv[j] - m); den += evv[j]; }
  float inv = 1.f / fmaxf(den, 1e-9f);
  float acc = 0.f;
#pragma unroll
  for (int j = 0; j < 8; ++j) acc += evv[j] * zsrc[(size_t)s[j] * 128 + c];
  acc *= inv;
  hout[(size_t)n * 128 + c] = acc > 0.f ? acc : (__expf(acc) - 1.f);
}

// ---------------- attention, CSR ----------------
__global__ __launch_bounds__(128)
void k_attn_csr(const float* __restrict__ zsrc, const float* __restrict__ el,
                const float* __restrict__ er, const int* __restrict__ rowptr,
                const int* __restrict__ eids, const int* __restrict__ rsrc,
                const float* __restrict__ ew, const float* __restrict__ ae,
                float* __restrict__ hout) {
  int n = blockIdx.x;
  int c = threadIdx.x;
  int h = c >> 4;
  int beg = rowptr[n], end = rowptr[n + 1];
  float aeh = ae[h];
  float erv = er[n * 8 + h];
  float m = -1e30f;
  for (int p = beg; p < end; ++p) {
    int eid = eids[p];
    float x = el[rsrc[eid] * 8 + h] + erv + ew[eid] * aeh;
    x = x > 0.f ? x : 0.2f * x;
    m = fmaxf(m, x);
  }
  float den = 0.f;
  for (int p = beg; p < end; ++p) {
    int eid = eids[p];
    float x = el[rsrc[eid] * 8 + h] + erv + ew[eid] * aeh;
    x = x > 0.f ? x : 0.2f * x;
    den += __expf(x - m);
  }
  float acc = 0.f;
  for (int p = beg; p < end; ++p) {
    int eid = eids[p];
    int sv = rsrc[eid];
    float x = el[sv * 8 + h] + erv + ew[eid] * aeh;
    x = x > 0.f ? x : 0.2f * x;
    acc += __expf(x - m) * zsrc[(size_t)sv * 128 + c];
  }
  acc /= fmaxf(den, 1e-9f);
  hout[(size_t)n * 128 + c] = acc > 0.f ? acc : (__expf(acc) - 1.f);
}

// ---------------- MFMA fused LN + FFN + residual ----------------
// out[32 rows] = h + relu(LN(h)@W1+b1)@W2 + b2 ; W1t[col<512][k<128], W2t[col<128][k<512] bf16
__global__ __launch_bounds__(256)
void k_ln_ffn_mfma(const float* __restrict__ h, const float* __restrict__ g,
                   const float* __restrict__ b,
                   const bf16_t* __restrict__ W1t, const float* __restrict__ b1,
                   const bf16_t* __restrict__ W2t, const float* __restrict__ b2,
                   float* __restrict__ out) {
  __shared__ float  hs[32][128];    // fp32 residual
  __shared__ bf16_t lnb[32][128];   // bf16 LN output, swizzled
  __shared__ bf16_t mid[32][512];   // bf16 relu(GEMM1), swizzled
  int r0 = blockIdx.x * 32;
  int tid = threadIdx.x;
  // stage fp32 (vectorized, unswizzled)
  for (int i = 0; i < 4; ++i) {
    int cid = tid + 256 * i;        // 1024 chunks of 4 floats
    int r = cid >> 5, c0 = (cid & 31) * 4;
    *(float4*)&hs[r][c0] = *(const float4*)&h[(size_t)(r0 + r) * 128 + c0];
  }
  __syncthreads();
  // LayerNorm: 32 rows x 8 lanes
  {
    int r = tid >> 3, lane = tid & 7;
    float sum = 0.f, sq = 0.f;
    for (int c = lane; c < 128; c += 8) { float v = hs[r][c]; sum += v; sq += v * v; }
#pragma unroll
    for (int o = 4; o >= 1; o >>= 1) { sum += __shfl_xor(sum, o); sq += __shfl_xor(sq, o); }
    float mu = sum * (1.f / 128.f);
    float var = sq * (1.f / 128.f) - mu * mu;
    float inv = rsqrtf(var + 1e-6f);
    int sw = (r & 7) << 3;
    for (int c = lane; c < 128; c += 8) {
      float v = (hs[r][c] - mu) * inv * g[c] + b[c];
      lnb[r][c ^ sw] = (bf16_t)v;
    }
  }
  __syncthreads();
  int w = tid >> 6, l = tid & 63, la = l & 15, lb = l >> 4;
  int swz = (la & 7) << 3;
  // GEMM1: mid[32, w*128..+128] = relu(lnb @ W1 + b1)
  {
    f32x4 acc1[2][8] = {};
#pragma unroll
    for (int ks = 0; ks < 4; ++ks) {
      int k0 = ks * 32 + lb * 8;
      bf16x8 a0 = *(const bf16x8*)&lnb[la][k0 ^ swz];
      bf16x8 a1 = *(const bf16x8*)&lnb[16 + la][k0 ^ swz];
#pragma unroll
      for (int ct = 0; ct < 8; ++ct) {
        int col = w * 128 + ct * 16 + la;
        bf16x8 bb = *(const bf16x8*)&W1t[(size_t)col * 128 + k0];
        acc1[0][ct] = __builtin_amdgcn_mfma_f32_16x16x32_bf16(a0, bb, acc1[0][ct], 0, 0, 0);
        acc1[1][ct] = __builtin_amdgcn_mfma_f32_16x16x32_bf16(a1, bb, acc1[1][ct], 0, 0, 0);
      }
    }
#pragma unroll
    for (int ct = 0; ct < 8; ++ct) {
      int col = w * 128 + ct * 16 + la;
      float bv = b1[col];
#pragma unroll
      for (int rt = 0; rt < 2; ++rt)
#pragma unroll
        for (int r = 0; r < 4; ++r) {
          int row = rt * 16 + lb * 4 + r;
          float v = acc1[rt][ct][r] + bv;
          mid[row][col ^ ((row & 7) << 3)] = (bf16_t)fmaxf(v, 0.f);
        }
    }
  }
  __syncthreads();
  // GEMM2: out[32, w*32..+32] = hs + mid @ W2 + b2
  {
    f32x4 acc2[2][2] = {};
#pragma unroll
    for (int ks = 0; ks < 16; ++ks) {
      int k0 = ks * 32 + lb * 8;
      bf16x8 a0 = *(const bf16x8*)&mid[la][k0 ^ swz];
      bf16x8 a1 = *(const bf16x8*)&mid[16 + la][k0 ^ swz];
#pragma unroll
      for (int ct = 0; ct < 2; ++ct) {
        int col = w * 32 + ct * 16 + la;
        bf16x8 bb = *(const bf16x8*)&W2t[(size_t)col * 512 + k0];
        acc2[0][ct] = __builtin_amdgcn_mfma_f32_16x16x32_bf16(a0, bb, acc2[0][ct], 0, 0, 0);
        acc2[1][ct] = __builtin_amdgcn_mfma_f32_16x16x32_bf16(a1, bb, acc2[1][ct], 0, 0, 0);
      }
    }
#pragma unroll
    for (int ct = 0; ct < 2; ++ct) {
      int col = w * 32 + ct * 16 + la;
      float bv = b2[col];
#pragma unroll
      for (int rt = 0; rt < 2; ++rt)
#pragma unroll
        for (int r = 0; r < 4; ++r) {
          int row = rt * 16 + lb * 4 + r;
          out[(size_t)(r0 + row) * 128 + col] = hs[row][col] + acc2[rt][ct][r] + bv;
        }
    }
  }
}

// ---------------- final head ----------------
__global__ __launch_bounds__(256)
void k_whout(const float* __restrict__ sup, const float* __restrict__ whW,
             const float* __restrict__ whb, float* __restrict__ out) {
  int wv = threadIdx.x >> 6, lane = threadIdx.x & 63;
  int r = blockIdx.x * 4 + wv;
  if (r >= S_N) return;
  const float* row = sup + (size_t)r * 128;
  float a0 = 0.f, a1 = 0.f;
  for (int d = lane; d < 128; d += 64) {
    float v = row[d];
    a0 += v * whW[d * 2];
    a1 += v * whW[d * 2 + 1];
  }
#pragma unroll
  for (int o = 32; o >= 1; o >>= 1) { a0 += __shfl_xor(a0, o); a1 += __shfl_xor(a1, o); }
  if (lane == 0) { out[r * 2] = a0 + whb[0]; out[r * 2 + 1] = a1 + whb[1]; }
}

// ---------------- CSR build ----------------
__global__ void k_count(const int* __restrict__ esrc, int* __restrict__ counts) {
  int t = blockIdx.x * 256 + threadIdx.x;
  if (t < E_NN) atomicAdd(&counts[esrc[t]], 1);
}

__global__ __launch_bounds__(1024)
void k_scan(const int* __restrict__ counts, int* __restrict__ rowptr) {
  __shared__ int wsum[16];
  __shared__ int carry;
  int tid = threadIdx.x, lane = tid & 63, w = tid >> 6;
  if (tid == 0) { carry = 0; rowptr[0] = 0; }
  __syncthreads();
  for (int base = 0; base < F_N; base += 1024) {
    int i = base + tid;
    int v = (i < F_N) ? counts[i] : 0;
    int s = v;
#pragma unroll
    for (int o = 1; o < 64; o <<= 1) { int t2 = __shfl_up(s, o); if (lane >= o) s += t2; }
    if (lane == 63) wsum[w] = s;
    __syncthreads();
    if (w == 0) {
      int t2 = (lane < 16) ? wsum[lane] : 0;
#pragma unroll
      for (int o = 1; o < 16; o <<= 1) { int u = __shfl_up(t2, o); if (lane >= o) t2 += u; }
      if (lane < 16) wsum[lane] = t2;
    }
    __syncthreads();
    int add = carry + (w > 0 ? wsum[w - 1] : 0);
    if (i < F_N) rowptr[i + 1] = s + add;
    int total = wsum[15];
    __syncthreads();
    if (tid == 0) carry += total;
    __syncthreads();
  }
}

__global__ void k_fill(const int* __restrict__ esrc, const int* __restrict__ rowptr,
                       int* __restrict__ fill, int* __restrict__ eids) {
  int t = blockIdx.x * 256 + threadIdx.x;
  if (t < E_NN) {
    int sv = esrc[t];
    int p = atomicAdd(&fill[sv], 1);
    eids[rowptr[sv] + p] = t;
  }
}

// ---------------- launch ----------------
extern "C" void kernel_launch(void* const* d_in, const int* in_sizes, int n_in,
                              void* d_out, int out_size, void* d_ws, size_t ws_size,
                              hipStream_t stream) {
  const int* fid = (const int*)d_in[0];
  const int* sid = (const int*)d_in[1];
  const int* uid = (const int*)d_in[2];
  const int* iid = (const int*)d_in[3];
  const int* e_src = (const int*)d_in[4];
  const int* e_dst = (const int*)d_in[5];
  const float* e_w = (const float*)d_in[6];
  const float* feat_tab = (const float*)d_in[7];
  const float* sent_tab = (const float*)d_in[8];
  const float* user_tab = (const float*)d_in[9];
  const float* item_tab = (const float*)d_in[10];
  const float* Wsp = (const float*)d_in[11];
  const float* bsp = (const float*)d_in[12];
  const float* Wup = (const float*)d_in[13];
  const float* Wip = (const float*)d_in[14];
  const float* w2s[10]; for (int i = 0; i < 10; ++i) w2s[i] = (const float*)d_in[15 + i];
  const float* s2w[10]; for (int i = 0; i < 10; ++i) s2w[i] = (const float*)d_in[25 + i];
  const float* whW = (const float*)d_in[35];
  const float* whb = (const float*)d_in[36];
  float* out = (float*)d_out;

  char* wp = (char*)d_ws;
  auto alloc = [&](size_t nbytes) -> void* {
    void* p = (void*)wp;
    wp += (nbytes + 255) & ~(size_t)255;
    return p;
  };
  float* featA = (float*)alloc((size_t)F_N * 128 * 4);
  float* supA  = (float*)alloc((size_t)NSUPN * 128 * 4);
  float* zf    = (float*)alloc((size_t)F_N * 128 * 4);
  float* zs    = (float*)alloc((size_t)NSUPN * 128 * 4);
  float* hbuf  = (float*)alloc((size_t)NSUPN * 128 * 4);
  float* elbig = (float*)alloc((size_t)NSUPN * 8 * 4);
  float* erbig = (float*)alloc((size_t)NSUPN * 8 * 4);
  float* atmpu = (float*)alloc((size_t)U_N * 128 * 4);
  float* atmpi = (float*)alloc((size_t)I_N * 128 * 4);
  float* fm    = (float*)alloc((size_t)(U_N + I_N) * 128 * 4);
  int* rowptr  = (int*)alloc((size_t)(F_N + 1) * 4);
  int* cnts    = (int*)alloc((size_t)2 * F_N * 4);
  int* eids    = (int*)alloc((size_t)E_NN * 4);
  bf16_t* WftA = (bf16_t*)alloc(128 * 128 * 2);
  bf16_t* WftB = (bf16_t*)alloc(128 * 128 * 2);
  bf16_t* W1tA = (bf16_t*)alloc(512 * 128 * 2);
  bf16_t* W1tB = (bf16_t*)alloc(512 * 128 * 2);
  bf16_t* W2tA = (bf16_t*)alloc(512 * 128 * 2);
  bf16_t* W2tB = (bf16_t*)alloc(512 * 128 * 2);

  // ---- weight conversions (bf16, transposed) ----
  k_build_wft<<<64, 256, 0, stream>>>(w2s[0], WftA);
  k_build_wft<<<64, 256, 0, stream>>>(s2w[0], WftB);
  k_conv_t<<<(512 * 128 + 255) / 256, 256, 0, stream>>>(w2s[4], W1tA, 128, 512);
  k_conv_t<<<(512 * 128 + 255) / 256, 256, 0, stream>>>(s2w[4], W1tB, 128, 512);
  k_conv_t<<<(512 * 128 + 255) / 256, 256, 0, stream>>>(w2s[6], W2tA, 512, 128);
  k_conv_t<<<(512 * 128 + 255) / 256, 256, 0, stream>>>(s2w[6], W2tB, 512, 128);

  // ---- stage A: init states (fp32) ----
  k_gather128<<<(F_N * 128 + 255) / 256, 256, 0, stream>>>(feat_tab, fid, featA, F_N);
  k_fmean<<<U_N + I_N, 128, 0, stream>>>(featA, e_src, fm);
  k_gemm_rows<true, true><<<S_N / 16, 128, 0, stream>>>(sent_tab, sid, 256, Wsp, bsp, supA, 256);
  k_addgather<<<(U_N * 128 + 255) / 256, 256, 0, stream>>>(user_tab, uid, fm, 0, atmpu, U_N);
  k_gemm_rows<false, false><<<U_N / 16, 128, 0, stream>>>(atmpu, nullptr, 128, Wup, nullptr,
                                                          supA + (size_t)S_N * 128, 128);
  k_addgather<<<(I_N * 128 + 255) / 256, 256, 0, stream>>>(item_tab, iid, fm, U_N, atmpi, I_N);
  k_gemm_rows<false, false><<<I_N / 16, 128, 0, stream>>>(atmpi, nullptr, 128, Wip, nullptr,
                                                          supA + (size_t)(S_N + U_N) * 128, 128);
  // ---- CSR over e_src ----
  hipMemsetAsync(cnts, 0, (size_t)2 * F_N * 4, stream);
  k_count<<<(E_NN + 255) / 256, 256, 0, stream>>>(e_src, cnts);
  k_scan<<<1, 1024, 0, stream>>>(cnts, rowptr);
  k_fill<<<(E_NN + 255) / 256, 256, 0, stream>>>(e_src, rowptr, cnts + F_N, eids);

  auto gat_w2s = [&](const float* hsrc, const float* hdst, float* outp) {
    k_zproj_mfma<<<F_N / 32, 256, 0, stream>>>(hsrc, WftA, zf);
    k_zproj_mfma<<<NSUPN / 32, 256, 0, stream>>>(hdst, WftA, zs);
    k_el<<<(F_N * 8 + 255) / 256, 256, 0, stream>>>(zf, w2s[1], elbig, F_N);
    k_el<<<(NSUPN * 8 + 255) / 256, 256, 0, stream>>>(zs, w2s[2], erbig, NSUPN);
    k_attn8<<<NSUPN, 128, 0, stream>>>(zf, elbig, erbig, e_src, e_w, w2s[3], hbuf);
    k_ln_ffn_mfma<<<NSUPN / 32, 256, 0, stream>>>(hbuf, w2s[8], w2s[9], W1tA, w2s[5], W2tA, w2s[7], outp);
  };
  auto gat_s2w = [&](const float* hsrc, const float* hdst, float* outp) {
    k_zproj_mfma<<<NSUPN / 32, 256, 0, stream>>>(hsrc, WftB, zs);
    k_zproj_mfma<<<F_N / 32, 256, 0, stream>>>(hdst, WftB, zf);
    k_el<<<(NSUPN * 8 + 255) / 256, 256, 0, stream>>>(zs, s2w[1], elbig, NSUPN);
    k_el<<<(F_N * 8 + 255) / 256, 256, 0, stream>>>(zf, s2w[2], erbig, F_N);
    k_attn_csr<<<F_N, 128, 0, stream>>>(zs, elbig, erbig, rowptr, eids, e_dst, e_w, s2w[3], hbuf);
    k_ln_ffn_mfma<<<F_N / 32, 256, 0, stream>>>(hbuf, s2w[8], s2w[9], W1tB, s2w[5], W2tB, s2w[7], outp);
  };

  gat_w2s(featA, supA, supA);
  gat_s2w(supA, featA, featA);
  gat_w2s(featA, supA, supA);

  k_whout<<<(S_N + 3) / 4, 256, 0, stream>>>(supA, whW, whb, out);
}

// Round 3
// 632.171 us; speedup vs baseline: 2.7235x; 1.3953x over previous
//
#include <hip/hip_runtime.h>
#include <hip/hip_bf16.h>

constexpr int F_N   = 20000;
constexpr int S_N   = 60000;
constexpr int U_N   = 2000;
constexpr int I_N   = 2000;
constexpr int NSUPN = 64000;
constexpr int E_NN  = NSUPN * 8;   // 512000
// HID=128, NH=8, DH=16, FFN=512

typedef __bf16 bf16_t;
typedef bf16_t bf16x8 __attribute__((ext_vector_type(8)));
typedef float  f32x4  __attribute__((ext_vector_type(4)));

// ---------------- gather / prep ----------------

__global__ void k_gather128(const float* __restrict__ tab, const int* __restrict__ idx,
                            float* __restrict__ out, int M) {
  int t = blockIdx.x * 256 + threadIdx.x;
  if (t >= M * 128) return;
  int r = t >> 7, c = t & 127;
  out[t] = tab[(size_t)idx[r] * 128 + c];
}

__global__ void k_fmean(const float* __restrict__ feat, const int* __restrict__ esrc,
                        float* __restrict__ fm) {
  int n = S_N + blockIdx.x;
  int c = threadIdx.x;
  float s = 0.f;
#pragma unroll
  for (int j = 0; j < 8; ++j) s += feat[(size_t)esrc[n * 8 + j] * 128 + c];
  fm[(size_t)blockIdx.x * 128 + c] = s * 0.125f;  // cnt == 8 exactly
}

__global__ void k_addgather(const float* __restrict__ tab, const int* __restrict__ idx,
                            const float* __restrict__ fm, int fmoff,
                            float* __restrict__ out, int M) {
  int t = blockIdx.x * 256 + threadIdx.x;
  if (t >= M * 128) return;
  int r = t >> 7, c = t & 127;
  out[t] = tab[(size_t)idx[r] * 128 + c] + fm[(size_t)(fmoff + r) * 128 + c];
}

// transpose-convert: out_bf16[c*K + k] = in_f32[k*C + c]
__global__ void k_conv_t(const float* __restrict__ in, bf16_t* __restrict__ out, int K, int C) {
  int t = blockIdx.x * 256 + threadIdx.x;
  if (t >= K * C) return;
  int c = t / K, k = t - c * K;
  out[t] = (bf16_t)in[(size_t)k * C + c];
}

// transpose + hi/lo bf16 split
__global__ void k_conv_t_split(const float* __restrict__ in, bf16_t* __restrict__ hi,
                               bf16_t* __restrict__ lo, int K, int C) {
  int t = blockIdx.x * 256 + threadIdx.x;
  if (t >= K * C) return;
  int c = t / K, k = t - c * K;
  float v = in[(size_t)k * C + c];
  bf16_t h = (bf16_t)v;
  hi[t] = h;
  lo[t] = (bf16_t)(v - (float)h);
}

// W [NH=8, HID=128, DH=16] -> Wft bf16 [col=128][d=128], Wft[col][d] = W[col>>4][d][col&15]
__global__ void k_build_wft(const float* __restrict__ W, bf16_t* __restrict__ out) {
  int t = blockIdx.x * 256 + threadIdx.x;
  if (t >= 128 * 128) return;
  int col = t >> 7, d = t & 127;
  out[t] = (bf16_t)W[((col >> 4) << 11) + (d << 4) + (col & 15)];
}

// ---------------- fp32 row-block GEMM (user/item init only, tiny) ----------------
template<bool GATHER, bool BIAS>
__global__ __launch_bounds__(128)
void k_gemm_rows(const float* __restrict__ A, const int* __restrict__ gidx, int ldA,
                 const float* __restrict__ B, const float* __restrict__ bias,
                 float* __restrict__ C, int K) {
  __shared__ float As[16 * 256];
  int r0 = blockIdx.x * 16;
  int tid = threadIdx.x;
  for (int idx = tid; idx < 16 * K; idx += 128) {
    int r = idx / K, k = idx - r * K;
    int row = r0 + r;
    size_t abase = GATHER ? (size_t)gidx[row] * ldA : (size_t)row * ldA;
    As[r * K + k] = A[abase + k];
  }
  __syncthreads();
  float acc[16];
#pragma unroll
  for (int r = 0; r < 16; ++r) acc[r] = 0.f;
  int c = tid;
  for (int k = 0; k < K; ++k) {
    float w = B[k * 128 + c];
#pragma unroll
    for (int r = 0; r < 16; ++r) acc[r] += As[r * K + k] * w;
  }
  float bv = BIAS ? bias[c] : 0.f;
#pragma unroll
  for (int r = 0; r < 16; ++r) C[(size_t)(r0 + r) * 128 + c] = acc[r] + bv;
}

// ---------------- sent-init: split-bf16 MFMA GEMM, gathered A, K=256 ----------------
__global__ __launch_bounds__(256)
void k_sent_mfma(const float* __restrict__ tab, const int* __restrict__ sid,
                 const bf16_t* __restrict__ Bhi, const bf16_t* __restrict__ Blo,
                 const float* __restrict__ bias, float* __restrict__ out) {
  __shared__ bf16_t Ahi[32][256];
  __shared__ bf16_t Alo[32][256];
  int r0 = blockIdx.x * 32;
  int tid = threadIdx.x;
  for (int i = 0; i < 4; ++i) {
    int cid = tid + 256 * i;            // 1024 chunks of 8 elems
    int r = cid >> 5, c0 = (cid & 31) * 8;
    const float* src = &tab[(size_t)sid[r0 + r] * 256 + c0];
    float4 v0 = *(const float4*)src, v1 = *(const float4*)(src + 4);
    float vv[8] = {v0.x, v0.y, v0.z, v0.w, v1.x, v1.y, v1.z, v1.w};
    bf16x8 hv, lv;
#pragma unroll
    for (int j = 0; j < 8; ++j) {
      bf16_t hb = (bf16_t)vv[j];
      hv[j] = hb;
      lv[j] = (bf16_t)(vv[j] - (float)hb);
    }
    int cs = c0 ^ ((r & 7) << 3);
    *(bf16x8*)&Ahi[r][cs] = hv;
    *(bf16x8*)&Alo[r][cs] = lv;
  }
  __syncthreads();
  int w = tid >> 6, l = tid & 63, la = l & 15, lb = l >> 4;
  int swz = (la & 7) << 3;
  f32x4 acc[2][2] = {};
#pragma unroll
  for (int ks = 0; ks < 8; ++ks) {
    int k0 = ks * 32 + lb * 8;
    int ka = k0 ^ swz;
    bf16x8 ah0 = *(const bf16x8*)&Ahi[la][ka];
    bf16x8 ah1 = *(const bf16x8*)&Ahi[16 + la][ka];
    bf16x8 al0 = *(const bf16x8*)&Alo[la][ka];
    bf16x8 al1 = *(const bf16x8*)&Alo[16 + la][ka];
#pragma unroll
    for (int ct = 0; ct < 2; ++ct) {
      int col = w * 32 + ct * 16 + la;
      bf16x8 bh = *(const bf16x8*)&Bhi[(size_t)col * 256 + k0];
      bf16x8 bl = *(const bf16x8*)&Blo[(size_t)col * 256 + k0];
      acc[0][ct] = __builtin_amdgcn_mfma_f32_16x16x32_bf16(ah0, bh, acc[0][ct], 0, 0, 0);
      acc[0][ct] = __builtin_amdgcn_mfma_f32_16x16x32_bf16(ah0, bl, acc[0][ct], 0, 0, 0);
      acc[0][ct] = __builtin_amdgcn_mfma_f32_16x16x32_bf16(al0, bh, acc[0][ct], 0, 0, 0);
      acc[1][ct] = __builtin_amdgcn_mfma_f32_16x16x32_bf16(ah1, bh, acc[1][ct], 0, 0, 0);
      acc[1][ct] = __builtin_amdgcn_mfma_f32_16x16x32_bf16(ah1, bl, acc[1][ct], 0, 0, 0);
      acc[1][ct] = __builtin_amdgcn_mfma_f32_16x16x32_bf16(al1, bh, acc[1][ct], 0, 0, 0);
    }
  }
#pragma unroll
  for (int ct = 0; ct < 2; ++ct) {
    int col = w * 32 + ct * 16 + la;
    float bv = bias[col];
#pragma unroll
    for (int rt = 0; rt < 2; ++rt)
#pragma unroll
      for (int r = 0; r < 4; ++r)
        out[(size_t)(r0 + rt * 16 + lb * 4 + r) * 128 + col] = acc[rt][ct][r] + bv;
  }
}

// ---------------- MFMA z-projection: z[N,128] = bf16(h) @ Wft^T (fp32 out) ----------------
__global__ __launch_bounds__(256)
void k_zproj_mfma(const float* __restrict__ h, const bf16_t* __restrict__ Wft,
                  float* __restrict__ z) {
  __shared__ bf16_t hb[32][128];
  int r0 = blockIdx.x * 32;
  int tid = threadIdx.x;
  for (int i = 0; i < 2; ++i) {
    int cid = tid + 256 * i;           // 512 chunks of 8 elems
    int r = cid >> 4, c0 = (cid & 15) * 8;
    const float* src = &h[(size_t)(r0 + r) * 128 + c0];
    float4 v0 = *(const float4*)src;
    float4 v1 = *(const float4*)(src + 4);
    bf16x8 bv = { (bf16_t)v0.x, (bf16_t)v0.y, (bf16_t)v0.z, (bf16_t)v0.w,
                  (bf16_t)v1.x, (bf16_t)v1.y, (bf16_t)v1.z, (bf16_t)v1.w };
    *(bf16x8*)&hb[r][c0 ^ ((r & 7) << 3)] = bv;
  }
  __syncthreads();
  int w = tid >> 6, l = tid & 63, la = l & 15, lb = l >> 4;
  int swz = (la & 7) << 3;
  f32x4 acc[2][2] = {};
#pragma unroll
  for (int ks = 0; ks < 4; ++ks) {
    int k0 = ks * 32 + lb * 8;
    bf16x8 a0 = *(const bf16x8*)&hb[la][k0 ^ swz];
    bf16x8 a1 = *(const bf16x8*)&hb[16 + la][k0 ^ swz];
#pragma unroll
    for (int ct = 0; ct < 2; ++ct) {
      int col = w * 32 + ct * 16 + la;
      bf16x8 bb = *(const bf16x8*)&Wft[(size_t)col * 128 + k0];
      acc[0][ct] = __builtin_amdgcn_mfma_f32_16x16x32_bf16(a0, bb, acc[0][ct], 0, 0, 0);
      acc[1][ct] = __builtin_amdgcn_mfma_f32_16x16x32_bf16(a1, bb, acc[1][ct], 0, 0, 0);
    }
  }
#pragma unroll
  for (int ct = 0; ct < 2; ++ct) {
    int col = w * 32 + ct * 16 + la;
#pragma unroll
    for (int rt = 0; rt < 2; ++rt)
#pragma unroll
      for (int r = 0; r < 4; ++r)
        z[(size_t)(r0 + rt * 16 + lb * 4 + r) * 128 + col] = acc[rt][ct][r];
  }
}

// ---------------- per-head attention logits ----------------
__global__ void k_el(const float* __restrict__ z, const float* __restrict__ a,
                     float* __restrict__ el, int N) {
  int t = blockIdx.x * 256 + threadIdx.x;
  if (t >= N * 8) return;
  int r = t >> 3, h = t & 7;
  const float* zr = z + (size_t)r * 128 + h * 16;
  const float* ah = a + h * 16;
  float s = 0.f;
#pragma unroll
  for (int e = 0; e < 16; ++e) s += zr[e] * ah[e];
  el[t] = s;
}

// ---------------- per-edge logits (leaky_relu already applied) ----------------
// w2s: natural edge order; src = e_src[eid] (feature), dst = eid>>3 (supernode)
__global__ void k_logits_w2s(const float* __restrict__ el, const float* __restrict__ er,
                             const int* __restrict__ esrc, const float* __restrict__ ew,
                             const float* __restrict__ ae, float* __restrict__ lg) {
  int t = blockIdx.x * 256 + threadIdx.x;
  if (t >= E_NN * 8) return;
  int eid = t >> 3, h = t & 7;
  float x = el[(size_t)esrc[eid] * 8 + h] + er[(size_t)(eid >> 3) * 8 + h] + ew[eid] * ae[h];
  lg[t] = x > 0.f ? x : 0.2f * x;
}
// s2w: CSR order; q=t>>3; eid=eids[q]; src = eid>>3 (supernode), dst = pdst[q] (feature)
__global__ void k_logits_s2w(const float* __restrict__ el, const float* __restrict__ er,
                             const int* __restrict__ eids, const int* __restrict__ pdst,
                             const float* __restrict__ ew, const float* __restrict__ ae,
                             float* __restrict__ lg) {
  int t = blockIdx.x * 256 + threadIdx.x;
  if (t >= E_NN * 8) return;
  int q = t >> 3, h = t & 7;
  int eid = eids[q];
  float x = el[(size_t)(eid >> 3) * 8 + h] + er[(size_t)pdst[q] * 8 + h] + ew[eid] * ae[h];
  lg[t] = x > 0.f ? x : 0.2f * x;
}

// ---------------- attention, fixed in-degree 8, precomputed logits ----------------
__global__ __launch_bounds__(256)
void k_attn8_v2(const float* __restrict__ zsrc, const float* __restrict__ lg,
                const int* __restrict__ esrc, float* __restrict__ hout) {
  int half = threadIdx.x >> 7;
  int n = blockIdx.x * 2 + half;
  int c = threadIdx.x & 127;
  int h = c >> 4;
  int s[8];
#pragma unroll
  for (int j = 0; j < 8; ++j) s[j] = esrc[n * 8 + j];
  float lv[8];
#pragma unroll
  for (int j = 0; j < 8; ++j) lv[j] = lg[(size_t)n * 64 + j * 8 + h];
  float m = -1e30f;
#pragma unroll
  for (int j = 0; j < 8; ++j) m = fmaxf(m, lv[j]);
  float den = 0.f;
#pragma unroll
  for (int j = 0; j < 8; ++j) { lv[j] = __expf(lv[j] - m); den += lv[j]; }
  float inv = 1.f / fmaxf(den, 1e-9f);
  float acc = 0.f;
#pragma unroll
  for (int j = 0; j < 8; ++j) acc += lv[j] * zsrc[(size_t)s[j] * 128 + c];
  acc *= inv;
  hout[(size_t)n * 128 + c] = acc > 0.f ? acc : (__expf(acc) - 1.f);
}

// ---------------- attention, CSR, precomputed logits, chunked online softmax ----------------
__global__ __launch_bounds__(128)
void k_attn_csr2(const float* __restrict__ zsrc, const float* __restrict__ lg,
                 const int* __restrict__ rowptr, const int* __restrict__ eids,
                 float* __restrict__ hout) {
  constexpr int CHUNK = 128;
  __shared__ float alg[CHUNK][8];
  __shared__ int   svs[CHUNK];
  int n = blockIdx.x;
  int c = threadIdx.x;
  int h = c >> 4;
  int beg = rowptr[n], deg = rowptr[n + 1] - beg;
  float acc = 0.f, mh = -1e30f, denh = 0.f;
  for (int c0 = 0; c0 < deg; c0 += CHUNK) {
    int cn = min(CHUNK, deg - c0);
    __syncthreads();
    for (int idx = c; idx < cn * 8; idx += 128)
      alg[idx >> 3][idx & 7] = lg[(size_t)(beg + c0) * 8 + idx];
    for (int j = c; j < cn; j += 128)
      svs[j] = eids[beg + c0 + j] >> 3;
    __syncthreads();
    float cm = mh;
    for (int j = 0; j < cn; ++j) cm = fmaxf(cm, alg[j][h]);
    float scale = __expf(mh - cm);   // first chunk: exp(-huge) = 0
    acc *= scale; denh *= scale; mh = cm;
#pragma unroll 4
    for (int j = 0; j < cn; ++j) {
      float p = __expf(alg[j][h] - mh);
      denh += p;
      acc += p * zsrc[(size_t)svs[j] * 128 + c];
    }
  }
  acc /= fmaxf(denh, 1e-9f);
  hout[(size_t)n * 128 + c] = acc > 0.f ? acc : (__expf(acc) - 1.f);
}

// ---------------- MFMA fused LN + FFN + residual ----------------
__global__ __launch_bounds__(256)
void k_ln_ffn_mfma(const float* __restrict__ h, const float* __restrict__ g,
                   const float* __restrict__ b,
                   const bf16_t* __restrict__ W1t, const float* __restrict__ b1,
                   const bf16_t* __restrict__ W2t, const float* __restrict__ b2,
                   float* __restrict__ out) {
  __shared__ float  hs[32][128];
  __shared__ bf16_t lnb[32][128];
  __shared__ bf16_t mid[32][512];
  int r0 = blockIdx.x * 32;
  int tid = threadIdx.x;
  for (int i = 0; i < 4; ++i) {
    int cid = tid + 256 * i;
    int r = cid >> 5, c0 = (cid & 31) * 4;
    *(float4*)&hs[r][c0] = *(const float4*)&h[(size_t)(r0 + r) * 128 + c0];
  }
  __syncthreads();
  {
    int r = tid >> 3, lane = tid & 7;
    float sum = 0.f, sq = 0.f;
    for (int c = lane; c < 128; c += 8) { float v = hs[r][c]; sum += v; sq += v * v; }
#pragma unroll
    for (int o = 4; o >= 1; o >>= 1) { sum += __shfl_xor(sum, o); sq += __shfl_xor(sq, o); }
    float mu = sum * (1.f / 128.f);
    float var = sq * (1.f / 128.f) - mu * mu;
    float inv = rsqrtf(var + 1e-6f);
    int sw = (r & 7) << 3;
    for (int c = lane; c < 128; c += 8) {
      float v = (hs[r][c] - mu) * inv * g[c] + b[c];
      lnb[r][c ^ sw] = (bf16_t)v;
    }
  }
  __syncthreads();
  int w = tid >> 6, l = tid & 63, la = l & 15, lb = l >> 4;
  int swz = (la & 7) << 3;
  {
    f32x4 acc1[2][8] = {};
#pragma unroll
    for (int ks = 0; ks < 4; ++ks) {
      int k0 = ks * 32 + lb * 8;
      bf16x8 a0 = *(const bf16x8*)&lnb[la][k0 ^ swz];
      bf16x8 a1 = *(const bf16x8*)&lnb[16 + la][k0 ^ swz];
#pragma unroll
      for (int ct = 0; ct < 8; ++ct) {
        int col = w * 128 + ct * 16 + la;
        bf16x8 bb = *(const bf16x8*)&W1t[(size_t)col * 128 + k0];
        acc1[0][ct] = __builtin_amdgcn_mfma_f32_16x16x32_bf16(a0, bb, acc1[0][ct], 0, 0, 0);
        acc1[1][ct] = __builtin_amdgcn_mfma_f32_16x16x32_bf16(a1, bb, acc1[1][ct], 0, 0, 0);
      }
    }
#pragma unroll
    for (int ct = 0; ct < 8; ++ct) {
      int col = w * 128 + ct * 16 + la;
      float bv = b1[col];
#pragma unroll
      for (int rt = 0; rt < 2; ++rt)
#pragma unroll
        for (int r = 0; r < 4; ++r) {
          int row = rt * 16 + lb * 4 + r;
          float v = acc1[rt][ct][r] + bv;
          mid[row][col ^ ((row & 7) << 3)] = (bf16_t)fmaxf(v, 0.f);
        }
    }
  }
  __syncthreads();
  {
    f32x4 acc2[2][2] = {};
#pragma unroll
    for (int ks = 0; ks < 16; ++ks) {
      int k0 = ks * 32 + lb * 8;
      bf16x8 a0 = *(const bf16x8*)&mid[la][k0 ^ swz];
      bf16x8 a1 = *(const bf16x8*)&mid[16 + la][k0 ^ swz];
#pragma unroll
      for (int ct = 0; ct < 2; ++ct) {
        int col = w * 32 + ct * 16 + la;
        bf16x8 bb = *(const bf16x8*)&W2t[(size_t)col * 512 + k0];
        acc2[0][ct] = __builtin_amdgcn_mfma_f32_16x16x32_bf16(a0, bb, acc2[0][ct], 0, 0, 0);
        acc2[1][ct] = __builtin_amdgcn_mfma_f32_16x16x32_bf16(a1, bb, acc2[1][ct], 0, 0, 0);
      }
    }
#pragma unroll
    for (int ct = 0; ct < 2; ++ct) {
      int col = w * 32 + ct * 16 + la;
      float bv = b2[col];
#pragma unroll
      for (int rt = 0; rt < 2; ++rt)
#pragma unroll
        for (int r = 0; r < 4; ++r) {
          int row = rt * 16 + lb * 4 + r;
          out[(size_t)(r0 + row) * 128 + col] = hs[row][col] + acc2[rt][ct][r] + bv;
        }
    }
  }
}

// ---------------- final head ----------------
__global__ __launch_bounds__(256)
void k_whout(const float* __restrict__ sup, const float* __restrict__ whW,
             const float* __restrict__ whb, float* __restrict__ out) {
  int wv = threadIdx.x >> 6, lane = threadIdx.x & 63;
  int r = blockIdx.x * 4 + wv;
  if (r >= S_N) return;
  const float* row = sup + (size_t)r * 128;
  float a0 = 0.f, a1 = 0.f;
  for (int d = lane; d < 128; d += 64) {
    float v = row[d];
    a0 += v * whW[d * 2];
    a1 += v * whW[d * 2 + 1];
  }
#pragma unroll
  for (int o = 32; o >= 1; o >>= 1) { a0 += __shfl_xor(a0, o); a1 += __shfl_xor(a1, o); }
  if (lane == 0) { out[r * 2] = a0 + whb[0]; out[r * 2 + 1] = a1 + whb[1]; }
}

// ---------------- CSR build ----------------
__global__ void k_count(const int* __restrict__ esrc, int* __restrict__ counts) {
  int t = blockIdx.x * 256 + threadIdx.x;
  if (t < E_NN) atomicAdd(&counts[esrc[t]], 1);
}

__global__ __launch_bounds__(1024)
void k_scan(const int* __restrict__ counts, int* __restrict__ rowptr) {
  __shared__ int wsum[16];
  __shared__ int carry;
  int tid = threadIdx.x, lane = tid & 63, w = tid >> 6;
  if (tid == 0) { carry = 0; rowptr[0] = 0; }
  __syncthreads();
  for (int base = 0; base < F_N; base += 1024) {
    int i = base + tid;
    int v = (i < F_N) ? counts[i] : 0;
    int s = v;
#pragma unroll
    for (int o = 1; o < 64; o <<= 1) { int t2 = __shfl_up(s, o); if (lane >= o) s += t2; }
    if (lane == 63) wsum[w] = s;
    __syncthreads();
    if (w == 0) {
      int t2 = (lane < 16) ? wsum[lane] : 0;
#pragma unroll
      for (int o = 1; o < 16; o <<= 1) { int u = __shfl_up(t2, o); if (lane >= o) t2 += u; }
      if (lane < 16) wsum[lane] = t2;
    }
    __syncthreads();
    int add = carry + (w > 0 ? wsum[w - 1] : 0);
    if (i < F_N) rowptr[i + 1] = s + add;
    int total = wsum[15];
    __syncthreads();
    if (tid == 0) carry += total;
    __syncthreads();
  }
}

__global__ void k_fill(const int* __restrict__ esrc, const int* __restrict__ rowptr,
                       int* __restrict__ fill, int* __restrict__ eids,
                       int* __restrict__ pdst) {
  int t = blockIdx.x * 256 + threadIdx.x;
  if (t < E_NN) {
    int sv = esrc[t];
    int p = atomicAdd(&fill[sv], 1);
    eids[rowptr[sv] + p] = t;
    pdst[rowptr[sv] + p] = sv;
  }
}

// ---------------- launch ----------------
extern "C" void kernel_launch(void* const* d_in, const int* in_sizes, int n_in,
                              void* d_out, int out_size, void* d_ws, size_t ws_size,
                              hipStream_t stream) {
  const int* fid = (const int*)d_in[0];
  const int* sid = (const int*)d_in[1];
  const int* uid = (const int*)d_in[2];
  const int* iid = (const int*)d_in[3];
  const int* e_src = (const int*)d_in[4];
  const int* e_dst = (const int*)d_in[5];
  const float* e_w = (const float*)d_in[6];
  const float* feat_tab = (const float*)d_in[7];
  const float* sent_tab = (const float*)d_in[8];
  const float* user_tab = (const float*)d_in[9];
  const float* item_tab = (const float*)d_in[10];
  const float* Wsp = (const float*)d_in[11];
  const float* bsp = (const float*)d_in[12];
  const float* Wup = (const float*)d_in[13];
  const float* Wip = (const float*)d_in[14];
  const float* w2s[10]; for (int i = 0; i < 10; ++i) w2s[i] = (const float*)d_in[15 + i];
  const float* s2w[10]; for (int i = 0; i < 10; ++i) s2w[i] = (const float*)d_in[25 + i];
  const float* whW = (const float*)d_in[35];
  const float* whb = (const float*)d_in[36];
  float* out = (float*)d_out;

  char* wp = (char*)d_ws;
  auto alloc = [&](size_t nbytes) -> void* {
    void* p = (void*)wp;
    wp += (nbytes + 255) & ~(size_t)255;
    return p;
  };
  float* featA = (float*)alloc((size_t)F_N * 128 * 4);
  float* supA  = (float*)alloc((size_t)NSUPN * 128 * 4);
  float* zf    = (float*)alloc((size_t)F_N * 128 * 4);
  float* zs    = (float*)alloc((size_t)NSUPN * 128 * 4);
  float* hbuf  = (float*)alloc((size_t)NSUPN * 128 * 4);
  float* elbig = (float*)alloc((size_t)NSUPN * 8 * 4);
  float* erbig = (float*)alloc((size_t)NSUPN * 8 * 4);
  float* lgbuf = (float*)alloc((size_t)E_NN * 8 * 4);
  float* atmpu = (float*)alloc((size_t)U_N * 128 * 4);
  float* atmpi = (float*)alloc((size_t)I_N * 128 * 4);
  float* fm    = (float*)alloc((size_t)(U_N + I_N) * 128 * 4);
  int* rowptr  = (int*)alloc((size_t)(F_N + 1) * 4);
  int* cnts    = (int*)alloc((size_t)2 * F_N * 4);
  int* eids    = (int*)alloc((size_t)E_NN * 4);
  int* pdst    = (int*)alloc((size_t)E_NN * 4);
  bf16_t* WftA = (bf16_t*)alloc(128 * 128 * 2);
  bf16_t* WftB = (bf16_t*)alloc(128 * 128 * 2);
  bf16_t* W1tA = (bf16_t*)alloc(512 * 128 * 2);
  bf16_t* W1tB = (bf16_t*)alloc(512 * 128 * 2);
  bf16_t* W2tA = (bf16_t*)alloc(512 * 128 * 2);
  bf16_t* W2tB = (bf16_t*)alloc(512 * 128 * 2);
  bf16_t* WspH = (bf16_t*)alloc(128 * 256 * 2);
  bf16_t* WspL = (bf16_t*)alloc(128 * 256 * 2);

  // ---- weight conversions ----
  k_build_wft<<<64, 256, 0, stream>>>(w2s[0], WftA);
  k_build_wft<<<64, 256, 0, stream>>>(s2w[0], WftB);
  k_conv_t<<<(512 * 128 + 255) / 256, 256, 0, stream>>>(w2s[4], W1tA, 128, 512);
  k_conv_t<<<(512 * 128 + 255) / 256, 256, 0, stream>>>(s2w[4], W1tB, 128, 512);
  k_conv_t<<<(512 * 128 + 255) / 256, 256, 0, stream>>>(w2s[6], W2tA, 512, 128);
  k_conv_t<<<(512 * 128 + 255) / 256, 256, 0, stream>>>(s2w[6], W2tB, 512, 128);
  k_conv_t_split<<<(256 * 128 + 255) / 256, 256, 0, stream>>>(Wsp, WspH, WspL, 256, 128);

  // ---- init states ----
  k_gather128<<<(F_N * 128 + 255) / 256, 256, 0, stream>>>(feat_tab, fid, featA, F_N);
  k_fmean<<<U_N + I_N, 128, 0, stream>>>(featA, e_src, fm);
  k_sent_mfma<<<S_N / 32, 256, 0, stream>>>(sent_tab, sid, WspH, WspL, bsp, supA);
  k_addgather<<<(U_N * 128 + 255) / 256, 256, 0, stream>>>(user_tab, uid, fm, 0, atmpu, U_N);
  k_gemm_rows<false, false><<<U_N / 16, 128, 0, stream>>>(atmpu, nullptr, 128, Wup, nullptr,
                                                          supA + (size_t)S_N * 128, 128);
  k_addgather<<<(I_N * 128 + 255) / 256, 256, 0, stream>>>(item_tab, iid, fm, U_N, atmpi, I_N);
  k_gemm_rows<false, false><<<I_N / 16, 128, 0, stream>>>(atmpi, nullptr, 128, Wip, nullptr,
                                                          supA + (size_t)(S_N + U_N) * 128, 128);
  // ---- CSR over e_src ----
  hipMemsetAsync(cnts, 0, (size_t)2 * F_N * 4, stream);
  k_count<<<(E_NN + 255) / 256, 256, 0, stream>>>(e_src, cnts);
  k_scan<<<1, 1024, 0, stream>>>(cnts, rowptr);
  k_fill<<<(E_NN + 255) / 256, 256, 0, stream>>>(e_src, rowptr, cnts + F_N, eids, pdst);

  auto gat_w2s = [&](const float* hsrc, const float* hdst, float* outp) {
    k_zproj_mfma<<<F_N / 32, 256, 0, stream>>>(hsrc, WftA, zf);
    k_zproj_mfma<<<NSUPN / 32, 256, 0, stream>>>(hdst, WftA, zs);
    k_el<<<(F_N * 8 + 255) / 256, 256, 0, stream>>>(zf, w2s[1], elbig, F_N);
    k_el<<<(NSUPN * 8 + 255) / 256, 256, 0, stream>>>(zs, w2s[2], erbig, NSUPN);
    k_logits_w2s<<<(E_NN * 8 + 255) / 256, 256, 0, stream>>>(elbig, erbig, e_src, e_w, w2s[3], lgbuf);
    k_attn8_v2<<<NSUPN / 2, 256, 0, stream>>>(zf, lgbuf, e_src, hbuf);
    k_ln_ffn_mfma<<<NSUPN / 32, 256, 0, stream>>>(hbuf, w2s[8], w2s[9], W1tA, w2s[5], W2tA, w2s[7], outp);
  };
  auto gat_s2w = [&](const float* hsrc, const float* hdst, float* outp) {
    k_zproj_mfma<<<NSUPN / 32, 256, 0, stream>>>(hsrc, WftB, zs);
    k_zproj_mfma<<<F_N / 32, 256, 0, stream>>>(hdst, WftB, zf);
    k_el<<<(NSUPN * 8 + 255) / 256, 256, 0, stream>>>(zs, s2w[1], elbig, NSUPN);
    k_el<<<(F_N * 8 + 255) / 256, 256, 0, stream>>>(zf, s2w[2], erbig, F_N);
    k_logits_s2w<<<(E_NN * 8 + 255) / 256, 256, 0, stream>>>(elbig, erbig, eids, pdst, e_w, s2w[3], lgbuf);
    k_attn_csr2<<<F_N, 128, 0, stream>>>(zs, lgbuf, rowptr, eids, hbuf);
    k_ln_ffn_mfma<<<F_N / 32, 256, 0, stream>>>(hbuf, s2w[8], s2w[9], W1tB, s2w[5], W2tB, s2w[7], outp);
  };

  gat_w2s(featA, supA, supA);
  gat_s2w(supA, featA, featA);
  gat_w2s(featA, supA, supA);

  k_whout<<<(S_N + 3) / 4, 256, 0, stream>>>(supA, whW, whb, out);
}